// Round 2
// baseline (14204.019 us; speedup 1.0000x reference)
//
#include <hip/hip_runtime.h>
#include <math.h>
#include <float.h>

// Problem constants (match reference)
#define M_TOK   32768
#define NSYM    8192
#define KDIM    1024
#define LAT     512

#define DECAY_F 0.995f
#define OMD_F   0.005f          // 1 - DECAY
#define GBS_F   0.7f            // GRAPH_BIAS_SCALE
#define EPS_F   1e-6f
#define TAU_F   0.125f          // fp64 rescore trigger on top-2 gap

// ---------------- codebook row norms (fp32, screening only) ----------------
__global__ void k_cnorm(const float* __restrict__ codebook,
                        float* __restrict__ cnorm) {
    int wave = threadIdx.x >> 6;    // 0..3
    int lane = threadIdx.x & 63;
    int s = blockIdx.x * 4 + wave;
    const float* row = &codebook[(size_t)s * KDIM];
    float acc = 0.0f;
#pragma unroll
    for (int p = 0; p < 4; ++p) {
        float4 v = *(const float4*)&row[p * 256 + lane * 4];
        acc += v.x * v.x + v.y * v.y + v.z * v.z + v.w * v.w;
    }
#pragma unroll
    for (int m = 32; m; m >>= 1) acc += __shfl_xor(acc, m, 64);
    if (lane == 0) cnorm[s] = acc;
}

// ---------------- fused GEMM + bias + argmin screen (fp32) ----------------
// tile: 64 tokens x 128 symbols per block, K staged in 16-deep LDS slabs.
#define TM 64
#define TN 128
#define KB 16

__global__ __launch_bounds__(256, 2) void k_dist_argmin(
    const float* __restrict__ z_real, const float* __restrict__ z_imag,
    const int* __restrict__ prev_idx, const float* __restrict__ codebook,
    const float* __restrict__ adjacency, const float* __restrict__ cnorm,
    float* __restrict__ out_idx,   // best index as float [M]
    float* __restrict__ scr1,      // best value [M]
    float* __restrict__ scr2)      // runner-up value [M]
{
    __shared__ __align__(16) float As[KB][TM + 4];   // [k][row]
    __shared__ __align__(16) float Bs[KB][TN + 4];   // [k][col]

    const int tid = threadIdx.x;
    const int ty = tid >> 4;        // 0..15 row group
    const int tx = tid & 15;        // 0..15 col group
    const int rowBase = blockIdx.x * TM;

    const int lr = tid >> 2;        // 0..63
    const int lk = (tid & 3) * 4;   // 0,4,8,12

    float v1[4], v2[4];
    int   i1[4];
#pragma unroll
    for (int r = 0; r < 4; ++r) { v1[r] = INFINITY; v2[r] = INFINITY; i1[r] = 0; }

    int prow[4];
#pragma unroll
    for (int r = 0; r < 4; ++r) prow[r] = prev_idx[rowBase + ty * 4 + r];

    for (int colBase = 0; colBase < NSYM; colBase += TN) {
        float acc[4][8];
#pragma unroll
        for (int r = 0; r < 4; ++r)
#pragma unroll
            for (int c = 0; c < 8; ++c) acc[r][c] = 0.0f;

        for (int k0 = 0; k0 < KDIM; k0 += KB) {
            const int kk = k0 + lk;
            float4 av;
            if (kk < LAT) av = *(const float4*)&z_real[(size_t)(rowBase + lr) * LAT + kk];
            else          av = *(const float4*)&z_imag[(size_t)(rowBase + lr) * LAT + kk - LAT];
            float4 bv0 = *(const float4*)&codebook[(size_t)(colBase + lr) * KDIM + kk];
            float4 bv1 = *(const float4*)&codebook[(size_t)(colBase + 64 + lr) * KDIM + kk];

            __syncthreads();
            As[lk + 0][lr] = av.x; As[lk + 1][lr] = av.y;
            As[lk + 2][lr] = av.z; As[lk + 3][lr] = av.w;
            Bs[lk + 0][lr] = bv0.x; Bs[lk + 1][lr] = bv0.y;
            Bs[lk + 2][lr] = bv0.z; Bs[lk + 3][lr] = bv0.w;
            Bs[lk + 0][64 + lr] = bv1.x; Bs[lk + 1][64 + lr] = bv1.y;
            Bs[lk + 2][64 + lr] = bv1.z; Bs[lk + 3][64 + lr] = bv1.w;
            __syncthreads();

#pragma unroll
            for (int k2 = 0; k2 < KB; ++k2) {
                float4 a  = *(const float4*)&As[k2][ty * 4];
                float4 b0 = *(const float4*)&Bs[k2][tx * 4];
                float4 b1 = *(const float4*)&Bs[k2][64 + tx * 4];
                float av4[4] = {a.x, a.y, a.z, a.w};
                float bv8[8] = {b0.x, b0.y, b0.z, b0.w, b1.x, b1.y, b1.z, b1.w};
#pragma unroll
                for (int r = 0; r < 4; ++r)
#pragma unroll
                    for (int c = 0; c < 8; ++c)
                        acc[r][c] = fmaf(av4[r], bv8[c], acc[r][c]);
            }
        }

        // scores + running best/runner-up for this chunk
#pragma unroll
        for (int r = 0; r < 4; ++r) {
            const float* arow = &adjacency[(size_t)prow[r] * NSYM + colBase];
            float4 ad0 = *(const float4*)&arow[tx * 4];
            float4 ad1 = *(const float4*)&arow[64 + tx * 4];
            float adv[8] = {ad0.x, ad0.y, ad0.z, ad0.w, ad1.x, ad1.y, ad1.z, ad1.w};
#pragma unroll
            for (int c = 0; c < 8; ++c) {
                int col = colBase + (c < 4 ? tx * 4 + c : 64 + tx * 4 + (c - 4));
                float bias = GBS_F / (1.0f + __expf(-adv[c]));
                float s = cnorm[col] - 2.0f * acc[r][c] - bias;
                if (s < v1[r]) { v2[r] = v1[r]; v1[r] = s; i1[r] = col; }
                else if (s < v2[r]) { v2[r] = s; }
            }
        }
    }

    // merge (v1,i1,v2) across the 16 tx lanes of each row group
#pragma unroll
    for (int r = 0; r < 4; ++r) {
        float a1 = v1[r], a2 = v2[r]; int ai = i1[r];
#pragma unroll
        for (int m = 1; m < 16; m <<= 1) {
            float o1 = __shfl_xor(a1, m, 16);
            int   oi = __shfl_xor(ai, m, 16);
            float o2 = __shfl_xor(a2, m, 16);
            float n2 = fminf(fminf(a2, o2), fmaxf(a1, o1));
            if (o1 < a1 || (o1 == a1 && oi < ai)) { a1 = o1; ai = oi; }
            a2 = n2;
        }
        if (tx == 0) {
            int row = rowBase + ty * 4 + r;
            out_idx[row] = (float)ai;
            scr1[row] = a1;
            scr2[row] = a2;
        }
    }
}

// ---------------- exact fp64 rescore for close calls ----------------
__global__ void k_fixup(const float* __restrict__ z_real,
                        const float* __restrict__ z_imag,
                        const int* __restrict__ prev_idx,
                        const float* __restrict__ codebook,
                        const float* __restrict__ adjacency,
                        const float* __restrict__ scr1,
                        const float* __restrict__ scr2,
                        float* __restrict__ out_idx) {
    const int tok = blockIdx.x;
    if (scr2[tok] - scr1[tok] >= TAU_F) return;   // uniform across block

    __shared__ double zsh[KDIM];
    __shared__ double bv[256];
    __shared__ int    bi[256];
    const int tid = threadIdx.x;

    for (int j = tid; j < LAT; j += 256) {
        zsh[j]       = (double)z_real[(size_t)tok * LAT + j];
        zsh[LAT + j] = (double)z_imag[(size_t)tok * LAT + j];
    }
    __syncthreads();

    const int prow = prev_idx[tok];
    double best = DBL_MAX; int bidx = NSYM;
    for (int j = tid; j < NSYM; j += 256) {
        const float* crow = &codebook[(size_t)j * KDIM];
        double dot = 0.0, cn = 0.0;
        for (int k = 0; k < KDIM; k += 4) {
            float4 c4 = *(const float4*)&crow[k];
            dot += (double)c4.x * zsh[k]     + (double)c4.y * zsh[k + 1]
                 + (double)c4.z * zsh[k + 2] + (double)c4.w * zsh[k + 3];
            cn  += (double)c4.x * c4.x + (double)c4.y * c4.y
                 + (double)c4.z * c4.z + (double)c4.w * c4.w;
        }
        double a = (double)adjacency[(size_t)prow * NSYM + j];
        double s = cn - 2.0 * dot - (double)GBS_F / (1.0 + exp(-a));
        if (s < best || (s == best && j < bidx)) { best = s; bidx = j; }
    }
    bv[tid] = best; bi[tid] = bidx;
    __syncthreads();
    for (int st = 128; st; st >>= 1) {
        if (tid < st) {
            if (bv[tid + st] < bv[tid] ||
                (bv[tid + st] == bv[tid] && bi[tid + st] < bi[tid])) {
                bv[tid] = bv[tid + st]; bi[tid] = bi[tid + st];
            }
        }
        __syncthreads();
    }
    if (tid == 0) out_idx[tok] = (float)bi[0];
}

// ---------------- init output accumulators ----------------
__global__ void k_init(const float* __restrict__ cluster_size,
                       const float* __restrict__ embed_avg,
                       float* __restrict__ out_cs,
                       float* __restrict__ out_ea,
                       float* __restrict__ out_loss) {
    int idx = blockIdx.x * blockDim.x + threadIdx.x;
    int stride = gridDim.x * blockDim.x;
    for (int i = idx; i < NSYM * KDIM; i += stride)
        out_ea[i] = embed_avg[i] * DECAY_F;
    for (int i = idx; i < NSYM; i += stride)
        out_cs[i] = cluster_size[i] * DECAY_F;
    if (idx == 0) out_loss[0] = 0.0f;
}

// ---------------- gather z_q, write output0, loss, scatter EMA ----------------
__global__ void k_scatter(const float* __restrict__ z_real,
                          const float* __restrict__ z_imag,
                          const float* __restrict__ codebook,
                          const float* __restrict__ idxf,
                          float* __restrict__ out_zc,
                          float* __restrict__ out_ea,
                          float* __restrict__ out_cs,
                          float* __restrict__ out_loss,
                          int interleaved) {
    const int i = blockIdx.x;
    const int mi = (int)idxf[i];
    float lsum = 0.0f;
    for (int j = threadIdx.x; j < LAT; j += blockDim.x) {
        float re = codebook[(size_t)mi * KDIM + j];
        float im = codebook[(size_t)mi * KDIM + LAT + j];
        float zr = z_real[(size_t)i * LAT + j];
        float zi = z_imag[(size_t)i * LAT + j];
        if (interleaved) {
            float2 zc = make_float2(re, im);
            *(float2*)&out_zc[((size_t)i * LAT + j) * 2] = zc;
        } else {
            out_zc[(size_t)i * LAT + j] = re;   // real part only
        }
        float dr = re - zr, di = im - zi;
        lsum += dr * dr + di * di;
        atomicAdd(&out_ea[(size_t)mi * KDIM + j], zr * OMD_F);
        atomicAdd(&out_ea[(size_t)mi * KDIM + LAT + j], zi * OMD_F);
    }
    __shared__ float red[4];
#pragma unroll
    for (int m = 32; m; m >>= 1) lsum += __shfl_xor(lsum, m, 64);
    int wave = threadIdx.x >> 6, lane = threadIdx.x & 63;
    if (lane == 0) red[wave] = lsum;
    __syncthreads();
    if (threadIdx.x == 0) {
        atomicAdd(out_loss, red[0] + red[1] + red[2] + red[3]);
        atomicAdd(&out_cs[mi], OMD_F);
    }
}

// ---------------- finalize: n_total, codebook divide, loss scale ----------------
__global__ void k_codebook(const float* __restrict__ out_ea,
                           const float* __restrict__ out_cs,
                           float* __restrict__ out_cb,
                           float* __restrict__ out_loss) {
    __shared__ float red[4];
    __shared__ float ntot_sh;
    const int tid = threadIdx.x;
    float s = 0.0f;
    for (int i = tid; i < NSYM; i += 256) s += out_cs[i];
#pragma unroll
    for (int m = 32; m; m >>= 1) s += __shfl_xor(s, m, 64);
    int wave = tid >> 6, lane = tid & 63;
    if (lane == 0) red[wave] = s;
    __syncthreads();
    if (tid == 0) ntot_sh = red[0] + red[1] + red[2] + red[3];
    __syncthreads();
    const float ntot = ntot_sh;
    const float denom = ntot + (float)NSYM * EPS_F;

    if (blockIdx.x == 0 && tid == 0)
        out_loss[0] = out_loss[0] * 1.25f / 33554432.0f;  // 1.25/(M*K)

    int idx = blockIdx.x * blockDim.x + tid;
    int stride = gridDim.x * blockDim.x;
    for (int i = idx; i < NSYM * KDIM; i += stride) {
        int sidx = i >> 10;
        float cs = (out_cs[sidx] + EPS_F) / denom * ntot;
        out_cb[i] = out_ea[i] / cs;
    }
}

extern "C" void kernel_launch(void* const* d_in, const int* in_sizes, int n_in,
                              void* d_out, int out_size, void* d_ws, size_t ws_size,
                              hipStream_t stream) {
    const float* z_real     = (const float*)d_in[0];
    const float* z_imag     = (const float*)d_in[1];
    const int*   prev_idx   = (const int*)d_in[2];
    const float* codebook   = (const float*)d_in[3];
    const float* cluster_sz = (const float*)d_in[4];
    const float* embed_avg  = (const float*)d_in[5];
    const float* adjacency  = (const float*)d_in[6];

    float* out = (float*)d_out;

    // Fixed tail: loss(1) + idx(32768) + cb(8388608) + cs(8192) + ea(8388608)
    const size_t REST = 1 + (size_t)M_TOK + (size_t)NSYM * KDIM + NSYM
                      + (size_t)NSYM * KDIM;                 // 16,818,177
    size_t zc_n = (size_t)out_size - REST;                   // floats for output 0
    const size_t n_z = (size_t)M_TOK * LAT;                  // 16,777,216
    int interleaved = (zc_n >= 2 * n_z) ? 1 : 0;             // complex64 as 2 floats?

    float* out_zc   = out;
    float* out_loss = out + zc_n;
    float* out_idx  = out + zc_n + 1;
    float* out_cb   = out + zc_n + 1 + M_TOK;
    float* out_cs   = out_cb + (size_t)NSYM * KDIM;
    float* out_ea   = out_cs + NSYM;

    // scratch carved out of out_cb (fully overwritten by k_codebook at the end)
    float* cnorm = out_cb;              // 8192 floats
    float* scr1  = out_cb + NSYM;       // 32768 floats
    float* scr2  = scr1 + M_TOK;        // 32768 floats

    k_cnorm<<<NSYM / 4, 256, 0, stream>>>(codebook, cnorm);
    k_dist_argmin<<<M_TOK / TM, 256, 0, stream>>>(z_real, z_imag, prev_idx,
                                                  codebook, adjacency, cnorm,
                                                  out_idx, scr1, scr2);
    k_fixup<<<M_TOK, 256, 0, stream>>>(z_real, z_imag, prev_idx, codebook,
                                       adjacency, scr1, scr2, out_idx);
    k_init<<<4096, 256, 0, stream>>>(cluster_sz, embed_avg, out_cs, out_ea, out_loss);
    k_scatter<<<M_TOK, 256, 0, stream>>>(z_real, z_imag, codebook, out_idx,
                                         out_zc, out_ea, out_cs, out_loss,
                                         interleaved);
    k_codebook<<<2048, 256, 0, stream>>>(out_ea, out_cs, out_cb, out_loss);
}

// Round 3
// 2367.364 us; speedup vs baseline: 5.9999x; 5.9999x over previous
//
#include <hip/hip_runtime.h>
#include <math.h>
#include <float.h>

#define M_TOK   32768
#define NSYM    8192
#define KDIM    1024
#define LAT     512

#define DECAY_F 0.995f
#define OMD_F   0.005f
#define GBS_F   0.7f
#define EPS_F   1e-6f
#define WIN_F   3.0f            // rescore window around screened min

typedef unsigned short u16;
typedef unsigned int   u32;
typedef short short8 __attribute__((ext_vector_type(8)));
typedef float f32x4  __attribute__((ext_vector_type(4)));

#define GLOAD_LDS16(g, l) \
    __builtin_amdgcn_global_load_lds((const __attribute__((address_space(1))) u32*)(g), \
                                     (__attribute__((address_space(3))) u32*)(l), 16, 0, 0)

__device__ __forceinline__ u16 f2bf(float f) {
    u32 u = __float_as_uint(f);
    return (u16)((u + 0x7FFF + ((u >> 16) & 1)) >> 16);   // round-to-nearest-even
}

// ---------------- convert A (z_real|z_imag) -> bf16 [32768][1024] ----------------
__global__ void k_convA(const float* __restrict__ zr, const float* __restrict__ zi,
                        u16* __restrict__ A) {
    size_t t = (size_t)blockIdx.x * 256 + threadIdx.x;    // 4,194,304 threads
    size_t base = t * 8;
    int tok = (int)(base >> 10);
    int k0  = (int)(base & 1023);
    const float* src = (k0 < 512) ? zr + (size_t)tok * 512 + k0
                                  : zi + (size_t)tok * 512 + (k0 - 512);
    float4 f0 = *(const float4*)src;
    float4 f1 = *(const float4*)(src + 4);
    u32 q0 = f2bf(f0.x) | ((u32)f2bf(f0.y) << 16);
    u32 q1 = f2bf(f0.z) | ((u32)f2bf(f0.w) << 16);
    u32 q2 = f2bf(f1.x) | ((u32)f2bf(f1.y) << 16);
    u32 q3 = f2bf(f1.z) | ((u32)f2bf(f1.w) << 16);
    *(uint4*)&A[base] = make_uint4(q0, q1, q2, q3);
}

// ---------------- convert B (codebook) -> bf16 [8192][1024] ----------------
__global__ void k_convB(const float* __restrict__ cb, u16* __restrict__ B) {
    size_t t = (size_t)blockIdx.x * 256 + threadIdx.x;    // 1,048,576 threads
    size_t base = t * 8;
    float4 f0 = *(const float4*)&cb[base];
    float4 f1 = *(const float4*)&cb[base + 4];
    u32 q0 = f2bf(f0.x) | ((u32)f2bf(f0.y) << 16);
    u32 q1 = f2bf(f0.z) | ((u32)f2bf(f0.w) << 16);
    u32 q2 = f2bf(f1.x) | ((u32)f2bf(f1.y) << 16);
    u32 q3 = f2bf(f1.z) | ((u32)f2bf(f1.w) << 16);
    *(uint4*)&B[base] = make_uint4(q0, q1, q2, q3);
}

// ---------------- codebook row norms (fp32) ----------------
__global__ void k_cnorm(const float* __restrict__ codebook,
                        float* __restrict__ cnorm) {
    int wave = threadIdx.x >> 6;
    int lane = threadIdx.x & 63;
    int s = blockIdx.x * 4 + wave;
    const float* row = &codebook[(size_t)s * KDIM];
    float acc = 0.0f;
#pragma unroll
    for (int p = 0; p < 4; ++p) {
        float4 v = *(const float4*)&row[p * 256 + lane * 4];
        acc += v.x * v.x + v.y * v.y + v.z * v.z + v.w * v.w;
    }
#pragma unroll
    for (int m = 32; m; m >>= 1) acc += __shfl_xor(acc, m, 64);
    if (lane == 0) cnorm[s] = acc;
}

// ---------------- bf16 MFMA screen: top-2 per 128-col chunk per token ----------------
// grid (256, 4): blockIdx.x -> 128 token-rows, blockIdx.y -> 16 of 64 col-chunks
__global__ __launch_bounds__(256, 2) void k_screen(
    const u16* __restrict__ Ah, const u16* __restrict__ Bh,
    const float* __restrict__ cnorm, const float* __restrict__ adjacency,
    const int* __restrict__ prev_idx,
    float* __restrict__ candV, float* __restrict__ candI)
{
    __shared__ __align__(16) unsigned char smA[16384];   // [128 rows][64 k] bf16, XOR-swizzled
    __shared__ __align__(16) unsigned char smB[16384];   // [128 cols][64 k] bf16, XOR-swizzled
    __shared__ float mv[128][4];
    __shared__ float mi[128][4];

    const int tid  = threadIdx.x;
    const int lane = tid & 63;
    const int w    = tid >> 6;          // wave 0..3
    const int wr   = w >> 1, wc = w & 1;
    const int row0 = blockIdx.x * 128;
    const int sBase = w * 256;          // staging slots owned by this wave

    int prow[16];
#pragma unroll
    for (int m = 0; m < 4; ++m)
#pragma unroll
        for (int j = 0; j < 4; ++j)
            prow[m * 4 + j] = prev_idx[row0 + wr * 64 + m * 16 + (lane >> 4) * 4 + j];

    for (int cc = 0; cc < 16; ++cc) {
        const int chunk = blockIdx.y * 16 + cc;
        const int colBase = chunk * 128;

        f32x4 acc[4][4];
#pragma unroll
        for (int m = 0; m < 4; ++m)
#pragma unroll
            for (int n = 0; n < 4; ++n) acc[m][n] = (f32x4){0.f, 0.f, 0.f, 0.f};

        for (int ks = 0; ks < 16; ++ks) {
            const int kk0 = ks * 64;
            __syncthreads();
            // stage A and B tiles: slot p -> row p>>3, phys chunk p&7 holds logical (p&7)^(row&7)
#pragma unroll
            for (int i = 0; i < 4; ++i) {
                int slot = sBase + i * 64 + lane;
                int r = slot >> 3;
                int c = (slot & 7) ^ (r & 7);
                const u16* ga = Ah + ((size_t)(row0 + r) * KDIM + kk0 + c * 8);
                GLOAD_LDS16(ga, smA + (size_t)(sBase + i * 64) * 16);
                const u16* gb = Bh + ((size_t)(colBase + r) * KDIM + kk0 + c * 8);
                GLOAD_LDS16(gb, smB + (size_t)(sBase + i * 64) * 16);
            }
            __syncthreads();
#pragma unroll
            for (int h = 0; h < 2; ++h) {
                short8 af[4], bfr[4];
#pragma unroll
                for (int m = 0; m < 4; ++m) {
                    int r = wr * 64 + m * 16 + (lane & 15);
                    int byte = r * 128 + h * 64 + (lane >> 4) * 16;
                    byte ^= (r & 7) << 4;
                    af[m] = *(const short8*)(smA + byte);
                }
#pragma unroll
                for (int n = 0; n < 4; ++n) {
                    int r = wc * 64 + n * 16 + (lane & 15);
                    int byte = r * 128 + h * 64 + (lane >> 4) * 16;
                    byte ^= (r & 7) << 4;
                    bfr[n] = *(const short8*)(smB + byte);
                }
#pragma unroll
                for (int m = 0; m < 4; ++m)
#pragma unroll
                    for (int n = 0; n < 4; ++n)
                        acc[m][n] = __builtin_amdgcn_mfma_f32_16x16x32_bf16(
                            af[m], bfr[n], acc[m][n], 0, 0, 0);
            }
        }

        // epilogue: scores + per-chunk top-2 per row
        float cn[4];
#pragma unroll
        for (int n = 0; n < 4; ++n)
            cn[n] = cnorm[colBase + wc * 64 + n * 16 + (lane & 15)];

#pragma unroll
        for (int m = 0; m < 4; ++m)
#pragma unroll
            for (int j = 0; j < 4; ++j) {
                int rowL = wr * 64 + m * 16 + (lane >> 4) * 4 + j;
                const float* arow = adjacency + (size_t)prow[m * 4 + j] * NSYM
                                  + colBase + wc * 64;
                float v1 = INFINITY, i1v = 0.f, v2 = INFINITY, i2v = 0.f;
#pragma unroll
                for (int n = 0; n < 4; ++n) {
                    float adv = arow[n * 16 + (lane & 15)];
                    float sg = 1.0f / (1.0f + __expf(-adv));
                    float s = cn[n] - 2.0f * acc[m][n][j] - GBS_F * sg;
                    float ci = (float)(colBase + wc * 64 + n * 16 + (lane & 15));
                    bool better = (s < v1) || (s == v1 && ci < i1v);
                    if (better) { v2 = v1; i2v = i1v; v1 = s; i1v = ci; }
                    else if (s < v2 || (s == v2 && ci < i2v)) { v2 = s; i2v = ci; }
                }
#pragma unroll
                for (int msk = 1; msk < 16; msk <<= 1) {
                    float o1 = __shfl_xor(v1, msk, 16),  oi1 = __shfl_xor(i1v, msk, 16);
                    float o2 = __shfl_xor(v2, msk, 16),  oi2 = __shfl_xor(i2v, msk, 16);
                    bool aw = (v1 < o1) || (v1 == o1 && i1v < oi1);
                    float n1 = aw ? v1 : o1,   ni1 = aw ? i1v : oi1;
                    float c2v = aw ? o1 : v1,  c2i = aw ? oi1 : i1v;
                    float s2v = aw ? v2 : o2,  s2i = aw ? i2v : oi2;
                    bool bw = (s2v < c2v) || (s2v == c2v && s2i < c2i);
                    v1 = n1; i1v = ni1;
                    v2 = bw ? s2v : c2v; i2v = bw ? s2i : c2i;
                }
                if ((lane & 15) == 0) {
                    mv[rowL][wc * 2] = v1;  mi[rowL][wc * 2] = i1v;
                    mv[rowL][wc * 2 + 1] = v2;  mi[rowL][wc * 2 + 1] = i2v;
                }
            }
        __syncthreads();
        if (tid < 128) {
            float a1 = mv[tid][0], ai1 = mi[tid][0], a2 = mv[tid][1], ai2 = mi[tid][1];
            float b1 = mv[tid][2], bi1 = mi[tid][2], b2 = mv[tid][3], bi2 = mi[tid][3];
            bool aw = (a1 < b1) || (a1 == b1 && ai1 < bi1);
            float n1 = aw ? a1 : b1,   ni1 = aw ? ai1 : bi1;
            float c2v = aw ? b1 : a1,  c2i = aw ? bi1 : ai1;
            float s2v = aw ? a2 : b2,  s2i = aw ? ai2 : bi2;
            bool bw = (s2v < c2v) || (s2v == c2v && s2i < c2i);
            size_t base = ((size_t)(row0 + tid)) * 128 + (size_t)chunk * 2;
            candV[base] = n1;  candI[base] = ni1;
            candV[base + 1] = bw ? s2v : c2v;
            candI[base + 1] = bw ? s2i : c2i;
        }
        // mv/mi reuse protected by the >=2 barriers inside the next chunk's K-loop
    }
}

// ---------------- select: exact fp64 rescore of candidates within window ----------------
__global__ void k_select(const float* __restrict__ zr, const float* __restrict__ zi,
                         const int* __restrict__ prev,
                         const float* __restrict__ codebook,
                         const float* __restrict__ adjacency,
                         const float* __restrict__ candV,
                         const float* __restrict__ candI,
                         float* __restrict__ out_idx) {
    int tok  = blockIdx.x * 4 + (threadIdx.x >> 6);
    int lane = threadIdx.x & 63;
    size_t cb = (size_t)tok * 128 + lane * 2;
    float2 vv = *(const float2*)&candV[cb];
    float2 ii = *(const float2*)&candI[cb];
    float v = vv.x, ix = ii.x;
    if (vv.y < v || (vv.y == v && ii.y < ix)) { v = vv.y; ix = ii.y; }
#pragma unroll
    for (int m = 1; m < 64; m <<= 1) {
        float ov = __shfl_xor(v, m, 64), oi = __shfl_xor(ix, m, 64);
        if (ov < v || (ov == v && oi < ix)) { v = ov; ix = oi; }
    }
    const float thresh = v + WIN_F;
    const int prw = prev[tok];
    double bestS = DBL_MAX; int bestI = 0x7FFFFFFF;
    for (int s = 0; s < 128; ++s) {
        float cv = __shfl((s & 1) ? vv.y : vv.x, s >> 1, 64);
        if (cv > thresh) continue;
        float cif = __shfl((s & 1) ? ii.y : ii.x, s >> 1, 64);
        int ci = (int)cif;
        const float* crow = codebook + (size_t)ci * KDIM;
        double dot = 0.0, cnd = 0.0;
        for (int t = lane; t < KDIM; t += 64) {
            double c = (double)crow[t];
            double z = (double)((t < LAT) ? zr[(size_t)tok * LAT + t]
                                          : zi[(size_t)tok * LAT + t - LAT]);
            dot += c * z; cnd += c * c;
        }
#pragma unroll
        for (int m = 32; m; m >>= 1) {
            dot += __shfl_xor(dot, m, 64);
            cnd += __shfl_xor(cnd, m, 64);
        }
        double a = (double)adjacency[(size_t)prw * NSYM + ci];
        double sc = cnd - 2.0 * dot - (double)GBS_F / (1.0 + exp(-a));
        if (sc < bestS || (sc == bestS && ci < bestI)) { bestS = sc; bestI = ci; }
    }
    if (lane == 0) out_idx[tok] = (float)bestI;
}

// ---------------- init output accumulators ----------------
__global__ void k_init(const float* __restrict__ cluster_size,
                       const float* __restrict__ embed_avg,
                       float* __restrict__ out_cs,
                       float* __restrict__ out_ea,
                       float* __restrict__ out_loss) {
    int idx = blockIdx.x * blockDim.x + threadIdx.x;
    int stride = gridDim.x * blockDim.x;
    for (int i = idx; i < NSYM * KDIM; i += stride)
        out_ea[i] = embed_avg[i] * DECAY_F;
    for (int i = idx; i < NSYM; i += stride)
        out_cs[i] = cluster_size[i] * DECAY_F;
    if (idx == 0) out_loss[0] = 0.0f;
}

// ---------------- gather z_q, write output0, loss, scatter EMA ----------------
__global__ void k_scatter(const float* __restrict__ z_real,
                          const float* __restrict__ z_imag,
                          const float* __restrict__ codebook,
                          const float* __restrict__ idxf,
                          float* __restrict__ out_zc,
                          float* __restrict__ out_ea,
                          float* __restrict__ out_cs,
                          float* __restrict__ out_loss,
                          int interleaved) {
    const int i = blockIdx.x;
    const int mi = (int)idxf[i];
    float lsum = 0.0f;
    for (int j = threadIdx.x; j < LAT; j += blockDim.x) {
        float re = codebook[(size_t)mi * KDIM + j];
        float im = codebook[(size_t)mi * KDIM + LAT + j];
        float zr = z_real[(size_t)i * LAT + j];
        float zi = z_imag[(size_t)i * LAT + j];
        if (interleaved) {
            float2 zc = make_float2(re, im);
            *(float2*)&out_zc[((size_t)i * LAT + j) * 2] = zc;
        } else {
            out_zc[(size_t)i * LAT + j] = re;
        }
        float dr = re - zr, di = im - zi;
        lsum += dr * dr + di * di;
        atomicAdd(&out_ea[(size_t)mi * KDIM + j], zr * OMD_F);
        atomicAdd(&out_ea[(size_t)mi * KDIM + LAT + j], zi * OMD_F);
    }
    __shared__ float red[4];
#pragma unroll
    for (int m = 32; m; m >>= 1) lsum += __shfl_xor(lsum, m, 64);
    int wave = threadIdx.x >> 6, lane = threadIdx.x & 63;
    if (lane == 0) red[wave] = lsum;
    __syncthreads();
    if (threadIdx.x == 0) {
        atomicAdd(out_loss, red[0] + red[1] + red[2] + red[3]);
        atomicAdd(&out_cs[mi], OMD_F);
    }
}

// ---------------- finalize ----------------
__global__ void k_codebook(const float* __restrict__ out_ea,
                           const float* __restrict__ out_cs,
                           float* __restrict__ out_cb,
                           float* __restrict__ out_loss) {
    __shared__ float red[4];
    __shared__ float ntot_sh;
    const int tid = threadIdx.x;
    float s = 0.0f;
    for (int i = tid; i < NSYM; i += 256) s += out_cs[i];
#pragma unroll
    for (int m = 32; m; m >>= 1) s += __shfl_xor(s, m, 64);
    int wave = tid >> 6, lane = tid & 63;
    if (lane == 0) red[wave] = s;
    __syncthreads();
    if (tid == 0) ntot_sh = red[0] + red[1] + red[2] + red[3];
    __syncthreads();
    const float ntot = ntot_sh;
    const float denom = ntot + (float)NSYM * EPS_F;

    if (blockIdx.x == 0 && tid == 0)
        out_loss[0] = out_loss[0] * 1.25f / 33554432.0f;   // 1.25/(M*K)

    int idx = blockIdx.x * blockDim.x + tid;
    int stride = gridDim.x * blockDim.x;
    for (int i = idx; i < NSYM * KDIM; i += stride) {
        int sidx = i >> 10;
        float cs = (out_cs[sidx] + EPS_F) / denom * ntot;
        out_cb[i] = out_ea[i] / cs;
    }
}

extern "C" void kernel_launch(void* const* d_in, const int* in_sizes, int n_in,
                              void* d_out, int out_size, void* d_ws, size_t ws_size,
                              hipStream_t stream) {
    const float* z_real     = (const float*)d_in[0];
    const float* z_imag     = (const float*)d_in[1];
    const int*   prev_idx   = (const int*)d_in[2];
    const float* codebook   = (const float*)d_in[3];
    const float* cluster_sz = (const float*)d_in[4];
    const float* embed_avg  = (const float*)d_in[5];
    const float* adjacency  = (const float*)d_in[6];

    float* out = (float*)d_out;

    const size_t REST = 1 + (size_t)M_TOK + (size_t)NSYM * KDIM + NSYM
                      + (size_t)NSYM * KDIM;               // 16,818,177
    size_t zc_n = (size_t)out_size - REST;
    const size_t n_z = (size_t)M_TOK * LAT;
    int interleaved = (zc_n >= 2 * n_z) ? 1 : 0;

    float* out_zc   = out;
    float* out_loss = out + zc_n;
    float* out_idx  = out + zc_n + 1;
    float* out_cb   = out + zc_n + 1 + M_TOK;
    float* out_cs   = out_cb + (size_t)NSYM * KDIM;
    float* out_ea   = out_cs + NSYM;

    // scratch carved out of output regions (each fully overwritten later):
    u16*   A_hi  = (u16*)out_zc;                 // 67.1 MB in zc region
    u16*   B_hi  = (u16*)out_cb;                 // 16.8 MB in cb region
    float* cnorm = out_cb + 4194304;             // 32 KB after B_hi
    float* candV = out_ea;                       // 16.8 MB
    float* candI = out_ea + 4194304;             // 16.8 MB

    k_convA<<<16384, 256, 0, stream>>>(z_real, z_imag, A_hi);
    k_convB<<<4096, 256, 0, stream>>>(codebook, B_hi);
    k_cnorm<<<NSYM / 4, 256, 0, stream>>>(codebook, cnorm);
    k_screen<<<dim3(M_TOK / 128, 4), 256, 0, stream>>>(A_hi, B_hi, cnorm,
                                                       adjacency, prev_idx,
                                                       candV, candI);
    k_select<<<M_TOK / 4, 256, 0, stream>>>(z_real, z_imag, prev_idx, codebook,
                                            adjacency, candV, candI, out_idx);
    k_init<<<4096, 256, 0, stream>>>(cluster_sz, embed_avg, out_cs, out_ea, out_loss);
    k_scatter<<<M_TOK, 256, 0, stream>>>(z_real, z_imag, codebook, out_idx,
                                         out_zc, out_ea, out_cs, out_loss,
                                         interleaved);
    k_codebook<<<2048, 256, 0, stream>>>(out_ea, out_cs, out_cb, out_loss);
}

// Round 4
// 1597.466 us; speedup vs baseline: 8.8916x; 1.4819x over previous
//
#include <hip/hip_runtime.h>
#include <math.h>
#include <float.h>

#define M_TOK   32768
#define NSYM    8192
#define KDIM    1024
#define LAT     512

#define DECAY_F 0.995f
#define OMD_F   0.005f
#define GBS_F   0.7f
#define EPS_F   1e-6f
#define WIN_F   4.0f            // unbiased-screen window: 0.7 bias + 6-sigma bf16 err

typedef unsigned short u16;
typedef unsigned int   u32;
typedef short short8 __attribute__((ext_vector_type(8)));
typedef float f32x4  __attribute__((ext_vector_type(4)));

#define GLOAD_LDS16(g, l) \
    __builtin_amdgcn_global_load_lds((const __attribute__((address_space(1))) u32*)(g), \
                                     (__attribute__((address_space(3))) u32*)(l), 16, 0, 0)

__device__ __forceinline__ u16 f2bf(float f) {
    u32 u = __float_as_uint(f);
    return (u16)((u + 0x7FFF + ((u >> 16) & 1)) >> 16);   // round-to-nearest-even
}

// ---------------- convert A (z_real|z_imag) -> bf16 [32768][1024] ----------------
__global__ void k_convA(const float* __restrict__ zr, const float* __restrict__ zi,
                        u16* __restrict__ A) {
    size_t t = (size_t)blockIdx.x * 256 + threadIdx.x;    // 4,194,304 threads
    size_t base = t * 8;
    int tok = (int)(base >> 10);
    int k0  = (int)(base & 1023);
    const float* src = (k0 < 512) ? zr + (size_t)tok * 512 + k0
                                  : zi + (size_t)tok * 512 + (k0 - 512);
    float4 f0 = *(const float4*)src;
    float4 f1 = *(const float4*)(src + 4);
    u32 q0 = f2bf(f0.x) | ((u32)f2bf(f0.y) << 16);
    u32 q1 = f2bf(f0.z) | ((u32)f2bf(f0.w) << 16);
    u32 q2 = f2bf(f1.x) | ((u32)f2bf(f1.y) << 16);
    u32 q3 = f2bf(f1.z) | ((u32)f2bf(f1.w) << 16);
    *(uint4*)&A[base] = make_uint4(q0, q1, q2, q3);
}

// ---------------- convert B (codebook) -> bf16 + fused row norms ----------------
__global__ void k_convB(const float* __restrict__ cb, u16* __restrict__ B,
                        float* __restrict__ cnorm) {
    size_t t = (size_t)blockIdx.x * 256 + threadIdx.x;    // 1,048,576 threads
    size_t base = t * 8;
    float4 f0 = *(const float4*)&cb[base];
    float4 f1 = *(const float4*)&cb[base + 4];
    u32 q0 = f2bf(f0.x) | ((u32)f2bf(f0.y) << 16);
    u32 q1 = f2bf(f0.z) | ((u32)f2bf(f0.w) << 16);
    u32 q2 = f2bf(f1.x) | ((u32)f2bf(f1.y) << 16);
    u32 q3 = f2bf(f1.z) | ((u32)f2bf(f1.w) << 16);
    *(uint4*)&B[base] = make_uint4(q0, q1, q2, q3);
    // fused cnorm: 128 consecutive threads cover one row (2 rows per block)
    float nrm = f0.x * f0.x + f0.y * f0.y + f0.z * f0.z + f0.w * f0.w
              + f1.x * f1.x + f1.y * f1.y + f1.z * f1.z + f1.w * f1.w;
#pragma unroll
    for (int m = 32; m; m >>= 1) nrm += __shfl_xor(nrm, m, 64);
    __shared__ float part[4];
    int lane = threadIdx.x & 63, w = threadIdx.x >> 6;
    if (lane == 0) part[w] = nrm;
    __syncthreads();
    if (threadIdx.x == 0)   cnorm[blockIdx.x * 2]     = part[0] + part[1];
    if (threadIdx.x == 128) cnorm[blockIdx.x * 2 + 1] = part[2] + part[3];
}

// ---------------- bf16 MFMA screen (UNBIASED): top-2 per 128-col chunk ----------------
// grid (256, 4): blockIdx.x -> 128 token-rows, blockIdx.y -> 16 of 64 col-chunks
// cand layout: candV[(chunk*2+s)*M + tok] (s=0 best, s=1 second), candI[chunk*M + tok]
__global__ __launch_bounds__(256, 4) void k_screen(
    const u16* __restrict__ Ah, const u16* __restrict__ Bh,
    const float* __restrict__ cnorm,
    float* __restrict__ candV, float* __restrict__ candI)
{
    __shared__ __align__(16) unsigned char smA[16384];   // [128 rows][64 k] bf16, XOR-swizzled
    __shared__ __align__(16) unsigned char smB[16384];   // [128 cols][64 k] bf16, XOR-swizzled
    __shared__ float mv[128][4];    // [row][wc*2+s]
    __shared__ float mi[128][2];    // [row][wc] best idx

    const int tid  = threadIdx.x;
    const int lane = tid & 63;
    const int w    = tid >> 6;
    const int wr   = w >> 1, wc = w & 1;
    const int row0 = blockIdx.x * 128;
    const int sBase = w * 256;

    for (int cc = 0; cc < 16; ++cc) {
        const int chunk = blockIdx.y * 16 + cc;
        const int colBase = chunk * 128;

        f32x4 acc[4][4];
#pragma unroll
        for (int m = 0; m < 4; ++m)
#pragma unroll
            for (int n = 0; n < 4; ++n) acc[m][n] = (f32x4){0.f, 0.f, 0.f, 0.f};

        for (int ks = 0; ks < 16; ++ks) {
            const int kk0 = ks * 64;
            __syncthreads();
#pragma unroll
            for (int i = 0; i < 4; ++i) {
                int slot = sBase + i * 64 + lane;
                int r = slot >> 3;
                int c = (slot & 7) ^ (r & 7);
                const u16* ga = Ah + ((size_t)(row0 + r) * KDIM + kk0 + c * 8);
                GLOAD_LDS16(ga, smA + (size_t)(sBase + i * 64) * 16);
                const u16* gb = Bh + ((size_t)(colBase + r) * KDIM + kk0 + c * 8);
                GLOAD_LDS16(gb, smB + (size_t)(sBase + i * 64) * 16);
            }
            __syncthreads();
#pragma unroll
            for (int h = 0; h < 2; ++h) {
                short8 af[4], bfr[4];
#pragma unroll
                for (int m = 0; m < 4; ++m) {
                    int r = wr * 64 + m * 16 + (lane & 15);
                    int byte = r * 128 + h * 64 + (lane >> 4) * 16;
                    byte ^= (r & 7) << 4;
                    af[m] = *(const short8*)(smA + byte);
                }
#pragma unroll
                for (int n = 0; n < 4; ++n) {
                    int r = wc * 64 + n * 16 + (lane & 15);
                    int byte = r * 128 + h * 64 + (lane >> 4) * 16;
                    byte ^= (r & 7) << 4;
                    bfr[n] = *(const short8*)(smB + byte);
                }
#pragma unroll
                for (int m = 0; m < 4; ++m)
#pragma unroll
                    for (int n = 0; n < 4; ++n)
                        acc[m][n] = __builtin_amdgcn_mfma_f32_16x16x32_bf16(
                            af[m], bfr[n], acc[m][n], 0, 0, 0);
            }
        }

        // epilogue: unbiased scores + per-chunk top-2 per row (value-only 2nd)
        float cn[4];
#pragma unroll
        for (int n = 0; n < 4; ++n)
            cn[n] = cnorm[colBase + wc * 64 + n * 16 + (lane & 15)];

#pragma unroll
        for (int m = 0; m < 4; ++m)
#pragma unroll
            for (int j = 0; j < 4; ++j) {
                int rowL = wr * 64 + m * 16 + (lane >> 4) * 4 + j;
                float v1 = INFINITY, v2 = INFINITY, i1v = 0.f;
#pragma unroll
                for (int n = 0; n < 4; ++n) {
                    float s = cn[n] - 2.0f * acc[m][n][j];
                    float ci = (float)(colBase + wc * 64 + n * 16 + (lane & 15));
                    if (s < v1) { v2 = v1; v1 = s; i1v = ci; }
                    else v2 = fminf(v2, s);
                }
#pragma unroll
                for (int msk = 1; msk < 16; msk <<= 1) {
                    float o1 = __shfl_xor(v1, msk, 16);
                    float oi = __shfl_xor(i1v, msk, 16);
                    float o2 = __shfl_xor(v2, msk, 16);
                    float n2 = fminf(fminf(v2, o2), fmaxf(v1, o1));
                    if (o1 < v1) { v1 = o1; i1v = oi; }
                    v2 = n2;
                }
                if ((lane & 15) == 0) {
                    mv[rowL][wc * 2] = v1;  mv[rowL][wc * 2 + 1] = v2;
                    mi[rowL][wc] = i1v;
                }
            }
        __syncthreads();
        if (tid < 128) {
            float a1 = mv[tid][0], a2 = mv[tid][1], ai = mi[tid][0];
            float b1 = mv[tid][2], b2 = mv[tid][3], bi = mi[tid][1];
            float best  = fminf(a1, b1);
            float bidx  = (b1 < a1) ? bi : ai;
            float secnd = fminf(fminf(a2, b2), fmaxf(a1, b1));
            size_t tcol = (size_t)(row0 + tid);
            candV[(size_t)(chunk * 2) * M_TOK + tcol]     = best;
            candV[(size_t)(chunk * 2 + 1) * M_TOK + tcol] = secnd;
            candI[(size_t)chunk * M_TOK + tcol]           = bidx;
        }
        // mv/mi reuse protected by barriers inside the next chunk's K-loop
    }
}

// ---------------- select: exact fp64 rescore (with bias) of windowed candidates ----------------
#define SEL_TOK 64
__global__ __launch_bounds__(256) void k_select(
    const float* __restrict__ zr, const float* __restrict__ zi,
    const int* __restrict__ prev,
    const float* __restrict__ codebook,
    const float* __restrict__ adjacency,
    const float* __restrict__ candV, const float* __restrict__ candI,
    float* __restrict__ out_idx)
{
    __shared__ float sv[128][SEL_TOK + 1];
    __shared__ float si[64][SEL_TOK + 1];
    const int tok0 = blockIdx.x * SEL_TOK;
    const int w = threadIdx.x >> 6, lane = threadIdx.x & 63;

    for (int it = 0; it < 32; ++it) {
        int e = it * 4 + w;
        sv[e][lane] = candV[(size_t)e * M_TOK + tok0 + lane];
    }
    for (int it = 0; it < 16; ++it) {
        int e = it * 4 + w;
        si[e][lane] = candI[(size_t)e * M_TOK + tok0 + lane];
    }
    __syncthreads();

    for (int tt = 0; tt < 16; ++tt) {
        const int t = w * 16 + tt;
        const int tok = tok0 + t;
        float v1 = sv[2 * lane][t];
        float v2 = sv[2 * lane + 1][t];
        float i1 = si[lane][t];

        float mm = v1;
#pragma unroll
        for (int m = 32; m; m >>= 1) mm = fminf(mm, __shfl_xor(mm, m, 64));
        const float thr = mm + WIN_F;

        unsigned long long candMask = __ballot(v1 <= thr);
        unsigned long long hidMask  = __ballot(v2 <= thr);

        double zreg[16];
#pragma unroll
        for (int j = 0; j < 8; ++j)
            zreg[j] = (double)zr[(size_t)tok * LAT + lane + 64 * j];
#pragma unroll
        for (int j = 0; j < 8; ++j)
            zreg[8 + j] = (double)zi[(size_t)tok * LAT + lane + 64 * j];
        const int prw = prev[tok];

        double bestS = DBL_MAX; int bestI = 0x7FFFFFFF;
        unsigned long long onlyC = candMask & ~hidMask;
        while (onlyC | hidMask) {
            int col0, ncols;
            if (hidMask) {
                int c = __ffsll(hidMask) - 1; hidMask &= hidMask - 1;
                col0 = c * 128; ncols = 128;
            } else {
                int c = __ffsll(onlyC) - 1; onlyC &= onlyC - 1;
                col0 = (int)__shfl(i1, c, 64); ncols = 1;
            }
            for (int q = 0; q < ncols; ++q) {
                int col = col0 + q;
                const float* crow = codebook + (size_t)col * KDIM;
                double dot = 0.0, cn2 = 0.0;
#pragma unroll
                for (int j = 0; j < 16; ++j) {
                    double c = (double)crow[lane + 64 * j];
                    dot += c * zreg[j]; cn2 += c * c;
                }
#pragma unroll
                for (int m = 32; m; m >>= 1) {
                    dot += __shfl_xor(dot, m, 64);
                    cn2 += __shfl_xor(cn2, m, 64);
                }
                double a = (double)adjacency[(size_t)prw * NSYM + col];
                double sc = cn2 - 2.0 * dot - (double)GBS_F / (1.0 + exp(-a));
                if (sc < bestS || (sc == bestS && col < bestI)) { bestS = sc; bestI = col; }
            }
        }
        if (lane == 0) out_idx[tok] = (float)bestI;
    }
}

// ---------------- init output accumulators ----------------
__global__ void k_init(const float* __restrict__ cluster_size,
                       const float* __restrict__ embed_avg,
                       float* __restrict__ out_cs,
                       float* __restrict__ out_ea,
                       float* __restrict__ out_loss) {
    int idx = blockIdx.x * blockDim.x + threadIdx.x;
    int stride = gridDim.x * blockDim.x;
    for (int i = idx; i < NSYM * KDIM; i += stride)
        out_ea[i] = embed_avg[i] * DECAY_F;
    for (int i = idx; i < NSYM; i += stride)
        out_cs[i] = cluster_size[i] * DECAY_F;
    if (idx == 0) out_loss[0] = 0.0f;
}

// ---------------- gather z_q, write output0, loss, scatter EMA ----------------
__global__ void k_scatter(const float* __restrict__ z_real,
                          const float* __restrict__ z_imag,
                          const float* __restrict__ codebook,
                          const float* __restrict__ idxf,
                          float* __restrict__ out_zc,
                          float* __restrict__ out_ea,
                          float* __restrict__ out_cs,
                          float* __restrict__ out_loss,
                          int interleaved) {
    const int i = blockIdx.x;
    const int mi = (int)idxf[i];
    float lsum = 0.0f;
    for (int j = threadIdx.x; j < LAT; j += blockDim.x) {
        float re = codebook[(size_t)mi * KDIM + j];
        float im = codebook[(size_t)mi * KDIM + LAT + j];
        float zr = z_real[(size_t)i * LAT + j];
        float zi = z_imag[(size_t)i * LAT + j];
        if (interleaved) {
            float2 zc = make_float2(re, im);
            *(float2*)&out_zc[((size_t)i * LAT + j) * 2] = zc;
        } else {
            out_zc[(size_t)i * LAT + j] = re;
        }
        float dr = re - zr, di = im - zi;
        lsum += dr * dr + di * di;
        atomicAdd(&out_ea[(size_t)mi * KDIM + j], zr * OMD_F);
        atomicAdd(&out_ea[(size_t)mi * KDIM + LAT + j], zi * OMD_F);
    }
    __shared__ float red[4];
#pragma unroll
    for (int m = 32; m; m >>= 1) lsum += __shfl_xor(lsum, m, 64);
    int wave = threadIdx.x >> 6, lane = threadIdx.x & 63;
    if (lane == 0) red[wave] = lsum;
    __syncthreads();
    if (threadIdx.x == 0) {
        atomicAdd(out_loss, red[0] + red[1] + red[2] + red[3]);
        atomicAdd(&out_cs[mi], OMD_F);
    }
}

// ---------------- finalize ----------------
__global__ void k_codebook(const float* __restrict__ out_ea,
                           const float* __restrict__ out_cs,
                           float* __restrict__ out_cb,
                           float* __restrict__ out_loss) {
    __shared__ float red[4];
    __shared__ float ntot_sh;
    const int tid = threadIdx.x;
    float s = 0.0f;
    for (int i = tid; i < NSYM; i += 256) s += out_cs[i];
#pragma unroll
    for (int m = 32; m; m >>= 1) s += __shfl_xor(s, m, 64);
    int wave = tid >> 6, lane = tid & 63;
    if (lane == 0) red[wave] = s;
    __syncthreads();
    if (tid == 0) ntot_sh = red[0] + red[1] + red[2] + red[3];
    __syncthreads();
    const float ntot = ntot_sh;
    const float denom = ntot + (float)NSYM * EPS_F;

    if (blockIdx.x == 0 && tid == 0)
        out_loss[0] = out_loss[0] * 1.25f / 33554432.0f;   // 1.25/(M*K)

    int idx = blockIdx.x * blockDim.x + tid;
    int stride = gridDim.x * blockDim.x;
    for (int i = idx; i < NSYM * KDIM; i += stride) {
        int sidx = i >> 10;
        float cs = (out_cs[sidx] + EPS_F) / denom * ntot;
        out_cb[i] = out_ea[i] / cs;
    }
}

extern "C" void kernel_launch(void* const* d_in, const int* in_sizes, int n_in,
                              void* d_out, int out_size, void* d_ws, size_t ws_size,
                              hipStream_t stream) {
    const float* z_real     = (const float*)d_in[0];
    const float* z_imag     = (const float*)d_in[1];
    const int*   prev_idx   = (const int*)d_in[2];
    const float* codebook   = (const float*)d_in[3];
    const float* cluster_sz = (const float*)d_in[4];
    const float* embed_avg  = (const float*)d_in[5];
    const float* adjacency  = (const float*)d_in[6];

    float* out = (float*)d_out;

    const size_t REST = 1 + (size_t)M_TOK + (size_t)NSYM * KDIM + NSYM
                      + (size_t)NSYM * KDIM;               // 16,818,177
    size_t zc_n = (size_t)out_size - REST;
    const size_t n_z = (size_t)M_TOK * LAT;
    int interleaved = (zc_n >= 2 * n_z) ? 1 : 0;

    float* out_zc   = out;
    float* out_loss = out + zc_n;
    float* out_idx  = out + zc_n + 1;
    float* out_cb   = out + zc_n + 1 + M_TOK;
    float* out_cs   = out_cb + (size_t)NSYM * KDIM;
    float* out_ea   = out_cs + NSYM;

    // scratch carved out of output regions (each fully overwritten later):
    u16*   A_hi  = (u16*)out_zc;                 // 67.1 MB in zc region
    u16*   B_hi  = (u16*)out_cb;                 // 16.8 MB in cb region
    float* cnorm = out_cb + 4194304;             // 32 KB after B_hi
    float* candV = out_ea;                       // 16.8 MB  [128][M]
    float* candI = out_ea + (size_t)128 * M_TOK; // 8.4 MB   [64][M]

    k_convA<<<16384, 256, 0, stream>>>(z_real, z_imag, A_hi);
    k_convB<<<4096, 256, 0, stream>>>(codebook, B_hi, cnorm);
    k_screen<<<dim3(M_TOK / 128, 4), 256, 0, stream>>>(A_hi, B_hi, cnorm,
                                                       candV, candI);
    k_select<<<M_TOK / SEL_TOK, 256, 0, stream>>>(z_real, z_imag, prev_idx,
                                                  codebook, adjacency,
                                                  candV, candI, out_idx);
    k_init<<<4096, 256, 0, stream>>>(cluster_sz, embed_avg, out_cs, out_ea, out_loss);
    k_scatter<<<M_TOK, 256, 0, stream>>>(z_real, z_imag, codebook, out_idx,
                                         out_zc, out_ea, out_cs, out_loss,
                                         interleaved);
    k_codebook<<<2048, 256, 0, stream>>>(out_ea, out_cs, out_cb, out_loss);
}

// Round 5
// 1521.342 us; speedup vs baseline: 9.3365x; 1.0500x over previous
//
#include <hip/hip_runtime.h>
#include <math.h>
#include <float.h>

#define M_TOK   32768
#define NSYM    8192
#define KDIM    1024
#define LAT     512

#define DECAY_F 0.995f
#define OMD_F   0.005f
#define GBS_F   0.7f
#define EPS_F   1e-6f
#define WIN_F   3.0f            // 0.7 bias + 2*(6-sigma bf16 screen err ~0.6) + margin

typedef unsigned short u16;
typedef unsigned int   u32;
typedef short short8 __attribute__((ext_vector_type(8)));
typedef float f32x4  __attribute__((ext_vector_type(4)));

#define GLOAD_LDS16(g, l) \
    __builtin_amdgcn_global_load_lds((const __attribute__((address_space(1))) u32*)(g), \
                                     (__attribute__((address_space(3))) u32*)(l), 16, 0, 0)

__device__ __forceinline__ u16 f2bf(float f) {
    u32 u = __float_as_uint(f);
    return (u16)((u + 0x7FFF + ((u >> 16) & 1)) >> 16);   // round-to-nearest-even
}

struct Top3 { float v1, v2, v3, i1, i2; };

__device__ __forceinline__ Top3 merge2(Top3 a, Top3 b) {
    Top3 r;
    bool aw = a.v1 <= b.v1;
    r.v1 = aw ? a.v1 : b.v1;  r.i1 = aw ? a.i1 : b.i1;
    float x1 = aw ? b.v1 : a.v1, xi1 = aw ? b.i1 : a.i1;   // loser-list top
    float x2 = aw ? a.v2 : b.v2, xi2 = aw ? a.i2 : b.i2;   // winner-list 2nd
    bool sw = x2 < x1;
    r.v2 = sw ? x2 : x1;  r.i2 = sw ? xi2 : xi1;
    float y1 = sw ? x1 : x2;
    float y2 = sw ? (aw ? a.v3 : b.v3) : (aw ? b.v2 : a.v2);
    r.v3 = fminf(y1, y2);
    return r;
}

// ---------------- convert A (z_real|z_imag) -> bf16 [32768][1024] ----------------
__global__ void k_convA(const float* __restrict__ zr, const float* __restrict__ zi,
                        u16* __restrict__ A) {
    size_t t = (size_t)blockIdx.x * 256 + threadIdx.x;
    size_t base = t * 8;
    int tok = (int)(base >> 10);
    int k0  = (int)(base & 1023);
    const float* src = (k0 < 512) ? zr + (size_t)tok * 512 + k0
                                  : zi + (size_t)tok * 512 + (k0 - 512);
    float4 f0 = *(const float4*)src;
    float4 f1 = *(const float4*)(src + 4);
    u32 q0 = f2bf(f0.x) | ((u32)f2bf(f0.y) << 16);
    u32 q1 = f2bf(f0.z) | ((u32)f2bf(f0.w) << 16);
    u32 q2 = f2bf(f1.x) | ((u32)f2bf(f1.y) << 16);
    u32 q3 = f2bf(f1.z) | ((u32)f2bf(f1.w) << 16);
    *(uint4*)&A[base] = make_uint4(q0, q1, q2, q3);
}

// ---------------- convert B (codebook) -> bf16 + fused row norms ----------------
__global__ void k_convB(const float* __restrict__ cb, u16* __restrict__ B,
                        float* __restrict__ cnorm) {
    size_t t = (size_t)blockIdx.x * 256 + threadIdx.x;
    size_t base = t * 8;
    float4 f0 = *(const float4*)&cb[base];
    float4 f1 = *(const float4*)&cb[base + 4];
    u32 q0 = f2bf(f0.x) | ((u32)f2bf(f0.y) << 16);
    u32 q1 = f2bf(f0.z) | ((u32)f2bf(f0.w) << 16);
    u32 q2 = f2bf(f1.x) | ((u32)f2bf(f1.y) << 16);
    u32 q3 = f2bf(f1.z) | ((u32)f2bf(f1.w) << 16);
    *(uint4*)&B[base] = make_uint4(q0, q1, q2, q3);
    float nrm = f0.x * f0.x + f0.y * f0.y + f0.z * f0.z + f0.w * f0.w
              + f1.x * f1.x + f1.y * f1.y + f1.z * f1.z + f1.w * f1.w;
#pragma unroll
    for (int m = 32; m; m >>= 1) nrm += __shfl_xor(nrm, m, 64);
    __shared__ float part[4];
    int lane = threadIdx.x & 63, w = threadIdx.x >> 6;
    if (lane == 0) part[w] = nrm;
    __syncthreads();
    if (threadIdx.x == 0)   cnorm[blockIdx.x * 2]     = part[0] + part[1];
    if (threadIdx.x == 128) cnorm[blockIdx.x * 2 + 1] = part[2] + part[3];
}

// ---------------- bf16 MFMA screen (UNBIASED): top-3 vals + top-2 idx per 128-col chunk ----------------
// 1D grid 1024, XCD-chunked swizzle: each XCD gets 32 consecutive bx (A-panel + B-chunk L2 reuse).
// cand layout: candV[(chunk*3+s)*M + tok], candI[(chunk*2+s)*M + tok] (u16)
__global__ __launch_bounds__(256, 4) void k_screen(
    const u16* __restrict__ Ah, const u16* __restrict__ Bh,
    const float* __restrict__ cnorm,
    float* __restrict__ candV, u16* __restrict__ candI)
{
    __shared__ __align__(16) unsigned char smA[16384];   // [128 rows][64 k] bf16, XOR-swizzled
    __shared__ __align__(16) unsigned char smB[16384];   // [128 cols][64 k] bf16, XOR-swizzled
    __shared__ float smv[128][2][3];
    __shared__ float smi[128][2][2];

    // XCD-aware swizzle: dispatch round-robins blockIdx%8 across XCDs.
    const int sblk = (blockIdx.x & 7) * 128 + (blockIdx.x >> 3);
    const int bx = sblk >> 2;          // 0..255 (token panel)
    const int by = sblk & 3;           // 0..3  (chunk quarter)

    const int tid  = threadIdx.x;
    const int lane = tid & 63;
    const int w    = tid >> 6;
    const int wr   = w >> 1, wc = w & 1;
    const int row0 = bx * 128;
    const int sBase = w * 256;

    for (int cc = 0; cc < 16; ++cc) {
        const int chunk = by * 16 + cc;
        const int colBase = chunk * 128;

        f32x4 acc[4][4];
#pragma unroll
        for (int m = 0; m < 4; ++m)
#pragma unroll
            for (int n = 0; n < 4; ++n) acc[m][n] = (f32x4){0.f, 0.f, 0.f, 0.f};

        for (int ks = 0; ks < 16; ++ks) {
            const int kk0 = ks * 64;
            __syncthreads();
#pragma unroll
            for (int i = 0; i < 4; ++i) {
                int slot = sBase + i * 64 + lane;
                int r = slot >> 3;
                int c = (slot & 7) ^ (r & 7);
                const u16* ga = Ah + ((size_t)(row0 + r) * KDIM + kk0 + c * 8);
                GLOAD_LDS16(ga, smA + (size_t)(sBase + i * 64) * 16);
                const u16* gb = Bh + ((size_t)(colBase + r) * KDIM + kk0 + c * 8);
                GLOAD_LDS16(gb, smB + (size_t)(sBase + i * 64) * 16);
            }
            __syncthreads();
#pragma unroll
            for (int h = 0; h < 2; ++h) {
                short8 af[4], bfr[4];
#pragma unroll
                for (int m = 0; m < 4; ++m) {
                    int r = wr * 64 + m * 16 + (lane & 15);
                    int byte = r * 128 + h * 64 + (lane >> 4) * 16;
                    byte ^= (r & 7) << 4;
                    af[m] = *(const short8*)(smA + byte);
                }
#pragma unroll
                for (int n = 0; n < 4; ++n) {
                    int r = wc * 64 + n * 16 + (lane & 15);
                    int byte = r * 128 + h * 64 + (lane >> 4) * 16;
                    byte ^= (r & 7) << 4;
                    bfr[n] = *(const short8*)(smB + byte);
                }
#pragma unroll
                for (int m = 0; m < 4; ++m)
#pragma unroll
                    for (int n = 0; n < 4; ++n)
                        acc[m][n] = __builtin_amdgcn_mfma_f32_16x16x32_bf16(
                            af[m], bfr[n], acc[m][n], 0, 0, 0);
            }
        }

        // epilogue: unbiased scores, per-row top-3 vals + top-2 idx
        float cn[4];
#pragma unroll
        for (int n = 0; n < 4; ++n)
            cn[n] = cnorm[colBase + wc * 64 + n * 16 + (lane & 15)];

#pragma unroll
        for (int m = 0; m < 4; ++m)
#pragma unroll
            for (int j = 0; j < 4; ++j) {
                int rowL = wr * 64 + m * 16 + (lane >> 4) * 4 + j;
                Top3 t = {INFINITY, INFINITY, INFINITY, 0.f, 0.f};
#pragma unroll
                for (int n = 0; n < 4; ++n) {
                    float s = cn[n] - 2.0f * acc[m][n][j];
                    float ci = (float)(colBase + wc * 64 + n * 16 + (lane & 15));
                    if (s < t.v1)      { t.v3 = t.v2; t.v2 = t.v1; t.i2 = t.i1; t.v1 = s; t.i1 = ci; }
                    else if (s < t.v2) { t.v3 = t.v2; t.v2 = s; t.i2 = ci; }
                    else               { t.v3 = fminf(t.v3, s); }
                }
#pragma unroll
                for (int msk = 1; msk < 16; msk <<= 1) {
                    Top3 o;
                    o.v1 = __shfl_xor(t.v1, msk, 16);
                    o.v2 = __shfl_xor(t.v2, msk, 16);
                    o.v3 = __shfl_xor(t.v3, msk, 16);
                    o.i1 = __shfl_xor(t.i1, msk, 16);
                    o.i2 = __shfl_xor(t.i2, msk, 16);
                    t = merge2(t, o);
                }
                if ((lane & 15) == 0) {
                    smv[rowL][wc][0] = t.v1; smv[rowL][wc][1] = t.v2; smv[rowL][wc][2] = t.v3;
                    smi[rowL][wc][0] = t.i1; smi[rowL][wc][1] = t.i2;
                }
            }
        __syncthreads();
        if (tid < 128) {
            Top3 a = {smv[tid][0][0], smv[tid][0][1], smv[tid][0][2],
                      smi[tid][0][0], smi[tid][0][1]};
            Top3 b = {smv[tid][1][0], smv[tid][1][1], smv[tid][1][2],
                      smi[tid][1][0], smi[tid][1][1]};
            Top3 r = merge2(a, b);
            size_t tcol = (size_t)(row0 + tid);
            candV[(size_t)(chunk * 3 + 0) * M_TOK + tcol] = r.v1;
            candV[(size_t)(chunk * 3 + 1) * M_TOK + tcol] = r.v2;
            candV[(size_t)(chunk * 3 + 2) * M_TOK + tcol] = r.v3;
            candI[(size_t)(chunk * 2 + 0) * M_TOK + tcol] = (u16)r.i1;
            candI[(size_t)(chunk * 2 + 1) * M_TOK + tcol] = (u16)r.i2;
        }
        // smv/smi reuse protected by barriers inside next chunk's K-loop
    }
}

// ---------------- zero scratch counters (after screen; A_bf16 area is dead) ----------------
__global__ void k_zero(u32* __restrict__ counts, u32* __restrict__ cursors,
                       float* __restrict__ out_loss) {
    int i = blockIdx.x * 256 + threadIdx.x;
    if (i < NSYM) { counts[i] = 0; cursors[i] = 0; }
    if (i == 0) out_loss[0] = 0.0f;
}

// ---------------- select: exact fp64 rescore (with bias) of windowed candidates ----------------
#define SEL_TOK 64
__device__ __forceinline__ void rescore(
    const float* __restrict__ codebook, const float* __restrict__ adjacency,
    const double* zreg, int prw, int col, int lane, double& bestS, int& bestI)
{
    const float* crow = codebook + (size_t)col * KDIM;
    double dot = 0.0, cn2 = 0.0;
#pragma unroll
    for (int j = 0; j < 16; ++j) {
        double c = (double)crow[lane + 64 * j];
        dot += c * zreg[j]; cn2 += c * c;
    }
#pragma unroll
    for (int m = 32; m; m >>= 1) {
        dot += __shfl_xor(dot, m, 64);
        cn2 += __shfl_xor(cn2, m, 64);
    }
    double a = (double)adjacency[(size_t)prw * NSYM + col];
    double sc = cn2 - 2.0 * dot - (double)GBS_F / (1.0 + exp(-a));
    if (sc < bestS || (sc == bestS && col < bestI)) { bestS = sc; bestI = col; }
}

__global__ __launch_bounds__(256) void k_select(
    const float* __restrict__ zr, const float* __restrict__ zi,
    const int* __restrict__ prev,
    const float* __restrict__ codebook,
    const float* __restrict__ adjacency,
    const float* __restrict__ candV, const u16* __restrict__ candI,
    float* __restrict__ out_idx, u32* __restrict__ counts)
{
    __shared__ float sv[192][SEL_TOK + 1];
    __shared__ u16   si[128][SEL_TOK + 2];
    const int tok0 = blockIdx.x * SEL_TOK;
    const int w = threadIdx.x >> 6, lane = threadIdx.x & 63;

    for (int e = w; e < 192; e += 4)
        sv[e][lane] = candV[(size_t)e * M_TOK + tok0 + lane];
    for (int e = w; e < 128; e += 4)
        si[e][lane] = candI[(size_t)e * M_TOK + tok0 + lane];
    __syncthreads();

    for (int tt = 0; tt < 16; ++tt) {
        const int t = w * 16 + tt;
        const int tok = tok0 + t;
        float v1 = sv[lane * 3 + 0][t];
        float v2 = sv[lane * 3 + 1][t];
        float v3 = sv[lane * 3 + 2][t];
        int   i1 = (int)si[lane * 2 + 0][t];
        int   i2 = (int)si[lane * 2 + 1][t];

        float mm = v1;
#pragma unroll
        for (int m = 32; m; m >>= 1) mm = fminf(mm, __shfl_xor(mm, m, 64));
        const float thr = mm + WIN_F;

        unsigned long long m1 = __ballot(v1 <= thr);
        unsigned long long m2 = __ballot(v2 <= thr);

        int bestI;
        if (__popcll(m1) == 1 && m2 == 0) {
            int c = __ffsll(m1) - 1;
            bestI = __shfl(i1, c, 64);
        } else {
            unsigned long long m3 = __ballot(v3 <= thr);
            double zreg[16];
#pragma unroll
            for (int j = 0; j < 8; ++j)
                zreg[j] = (double)zr[(size_t)tok * LAT + lane + 64 * j];
#pragma unroll
            for (int j = 0; j < 8; ++j)
                zreg[8 + j] = (double)zi[(size_t)tok * LAT + lane + 64 * j];
            const int prw = prev[tok];

            double bestS = DBL_MAX; bestI = 0x7FFFFFFF;
            unsigned long long mm1 = m1, mm2 = m2 & ~m3, mm3 = m3;
            while (mm1) { int c = __ffsll(mm1) - 1; mm1 &= mm1 - 1;
                rescore(codebook, adjacency, zreg, prw, __shfl(i1, c, 64), lane, bestS, bestI); }
            while (mm2) { int c = __ffsll(mm2) - 1; mm2 &= mm2 - 1;
                rescore(codebook, adjacency, zreg, prw, __shfl(i2, c, 64), lane, bestS, bestI); }
            while (mm3) { int c = __ffsll(mm3) - 1; mm3 &= mm3 - 1;
                for (int q = 0; q < 128; ++q)
                    rescore(codebook, adjacency, zreg, prw, c * 128 + q, lane, bestS, bestI); }
        }
        if (lane == 0) {
            out_idx[tok] = (float)bestI;
            atomicAdd(&counts[bestI], 1u);
        }
    }
}

// ---------------- scan: offsets, new_cluster_size, n_total ----------------
__global__ __launch_bounds__(1024) void k_scan(
    const u32* __restrict__ counts, const float* __restrict__ cs_old,
    float* __restrict__ out_cs, u32* __restrict__ offsets,
    float* __restrict__ scal)     // scal[0]=ntot, scal[1]=denom
{
    const int tid = threadIdx.x;
    const int lane = tid & 63, w = tid >> 6;
    const int base = tid * 8;
    u32 c[8], pre[8], T = 0;
#pragma unroll
    for (int q = 0; q < 8; ++q) { c[q] = counts[base + q]; pre[q] = T; T += c[q]; }
    u32 inc = T;
#pragma unroll
    for (int d = 1; d < 64; d <<= 1) {
        u32 v = __shfl_up(inc, d, 64);
        if (lane >= d) inc += v;
    }
    __shared__ u32 wt[16];
    if (lane == 63) wt[w] = inc;
    __syncthreads();
    if (tid < 16) {
        u32 v = wt[tid];
#pragma unroll
        for (int d = 1; d < 16; d <<= 1) {
            u32 o = __shfl_up(v, d, 16);
            if (tid >= d) v += o;
        }
        wt[tid] = v;
    }
    __syncthreads();
    u32 ex = (w ? wt[w - 1] : 0) + inc - T;
#pragma unroll
    for (int q = 0; q < 8; ++q) offsets[base + q] = ex + pre[q];

    float nt = 0.0f;
#pragma unroll
    for (int q = 0; q < 8; ++q) {
        float ncs = cs_old[base + q] * DECAY_F + OMD_F * (float)c[q];
        out_cs[base + q] = ncs;
        nt += ncs;
    }
#pragma unroll
    for (int m = 32; m; m >>= 1) nt += __shfl_xor(nt, m, 64);
    __shared__ float red[16];
    if (lane == 0) red[w] = nt;
    __syncthreads();
    if (tid == 0) {
        float s = 0.0f;
#pragma unroll
        for (int i = 0; i < 16; ++i) s += red[i];
        scal[0] = s;
        scal[1] = s + (float)NSYM * EPS_F;
    }
}

// ---------------- place: token lists per symbol ----------------
__global__ void k_place(const float* __restrict__ idxf, const u32* __restrict__ offsets,
                        u32* __restrict__ cursors, u32* __restrict__ list) {
    int t = blockIdx.x * 256 + threadIdx.x;
    int s = (int)idxf[t];
    u32 slot = atomicAdd(&cursors[s], 1u);
    list[offsets[s] + slot] = (u32)t;
}

// ---------------- emit: new_embed_avg + new_codebook per symbol (no atomics) ----------------
__global__ __launch_bounds__(256) void k_emit(
    const float* __restrict__ zr, const float* __restrict__ zi,
    const float* __restrict__ embed_avg,
    const u32* __restrict__ counts, const u32* __restrict__ offsets,
    const u32* __restrict__ list, const float* __restrict__ out_cs,
    const float* __restrict__ scal,
    float* __restrict__ out_ea, float* __restrict__ out_cb)
{
    const int s = blockIdx.x;
    const u32 cnt = counts[s], off = offsets[s];
    const int j = threadIdx.x * 4;
    float a0 = 0.f, a1 = 0.f, a2 = 0.f, a3 = 0.f;
    for (u32 n = 0; n < cnt; ++n) {
        int t = (int)list[off + n];
        const float* src = (j < 512) ? zr + (size_t)t * 512 + j
                                     : zi + (size_t)t * 512 + (j - 512);
        float4 v = *(const float4*)src;
        a0 += v.x; a1 += v.y; a2 += v.z; a3 += v.w;
    }
    float4 ea = *(const float4*)&embed_avg[(size_t)s * KDIM + j];
    float4 nea = make_float4(ea.x * DECAY_F + a0 * OMD_F,
                             ea.y * DECAY_F + a1 * OMD_F,
                             ea.z * DECAY_F + a2 * OMD_F,
                             ea.w * DECAY_F + a3 * OMD_F);
    *(float4*)&out_ea[(size_t)s * KDIM + j] = nea;
    float ntot = scal[0], denom = scal[1];
    float cs = (out_cs[s] + EPS_F) / denom * ntot;
    float inv = 1.0f / cs;
    *(float4*)&out_cb[(size_t)s * KDIM + j] =
        make_float4(nea.x * inv, nea.y * inv, nea.z * inv, nea.w * inv);
}

// ---------------- zq: gather codebook rows, write output0, loss ----------------
__global__ __launch_bounds__(256) void k_zq(
    const float* __restrict__ zr, const float* __restrict__ zi,
    const float* __restrict__ codebook, const float* __restrict__ idxf,
    float* __restrict__ out_zc, float* __restrict__ out_loss, int interleaved)
{
    const int w = threadIdx.x >> 6, lane = threadIdx.x & 63;
    const int tok = blockIdx.x * 4 + w;
    const int mi = (int)idxf[tok];
    const int j0 = lane * 8;
    float4 re0 = *(const float4*)&codebook[(size_t)mi * KDIM + j0];
    float4 re1 = *(const float4*)&codebook[(size_t)mi * KDIM + j0 + 4];
    float4 im0 = *(const float4*)&codebook[(size_t)mi * KDIM + LAT + j0];
    float4 im1 = *(const float4*)&codebook[(size_t)mi * KDIM + LAT + j0 + 4];
    float4 zr0 = *(const float4*)&zr[(size_t)tok * LAT + j0];
    float4 zr1 = *(const float4*)&zr[(size_t)tok * LAT + j0 + 4];
    float4 zi0 = *(const float4*)&zi[(size_t)tok * LAT + j0];
    float4 zi1 = *(const float4*)&zi[(size_t)tok * LAT + j0 + 4];
    if (interleaved) {
        float2* dst = (float2*)out_zc + (size_t)tok * LAT + j0;
        dst[0] = make_float2(re0.x, im0.x); dst[1] = make_float2(re0.y, im0.y);
        dst[2] = make_float2(re0.z, im0.z); dst[3] = make_float2(re0.w, im0.w);
        dst[4] = make_float2(re1.x, im1.x); dst[5] = make_float2(re1.y, im1.y);
        dst[6] = make_float2(re1.z, im1.z); dst[7] = make_float2(re1.w, im1.w);
    } else {
        *(float4*)&out_zc[(size_t)tok * LAT + j0]     = re0;
        *(float4*)&out_zc[(size_t)tok * LAT + j0 + 4] = re1;
    }
    float l = 0.f;
    l += (re0.x-zr0.x)*(re0.x-zr0.x) + (re0.y-zr0.y)*(re0.y-zr0.y)
       + (re0.z-zr0.z)*(re0.z-zr0.z) + (re0.w-zr0.w)*(re0.w-zr0.w);
    l += (re1.x-zr1.x)*(re1.x-zr1.x) + (re1.y-zr1.y)*(re1.y-zr1.y)
       + (re1.z-zr1.z)*(re1.z-zr1.z) + (re1.w-zr1.w)*(re1.w-zr1.w);
    l += (im0.x-zi0.x)*(im0.x-zi0.x) + (im0.y-zi0.y)*(im0.y-zi0.y)
       + (im0.z-zi0.z)*(im0.z-zi0.z) + (im0.w-zi0.w)*(im0.w-zi0.w);
    l += (im1.x-zi1.x)*(im1.x-zi1.x) + (im1.y-zi1.y)*(im1.y-zi1.y)
       + (im1.z-zi1.z)*(im1.z-zi1.z) + (im1.w-zi1.w)*(im1.w-zi1.w);
#pragma unroll
    for (int m = 32; m; m >>= 1) l += __shfl_xor(l, m, 64);
    if (lane == 0) atomicAdd(out_loss, l);
}

// ---------------- finalize loss ----------------
__global__ void k_fin(float* __restrict__ out_loss) {
    out_loss[0] = out_loss[0] * 1.25f / 33554432.0f;   // *(1+0.25)/(M*KDIM)
}

extern "C" void kernel_launch(void* const* d_in, const int* in_sizes, int n_in,
                              void* d_out, int out_size, void* d_ws, size_t ws_size,
                              hipStream_t stream) {
    const float* z_real     = (const float*)d_in[0];
    const float* z_imag     = (const float*)d_in[1];
    const int*   prev_idx   = (const int*)d_in[2];
    const float* codebook   = (const float*)d_in[3];
    const float* cluster_sz = (const float*)d_in[4];
    const float* embed_avg  = (const float*)d_in[5];
    const float* adjacency  = (const float*)d_in[6];

    float* out = (float*)d_out;

    const size_t REST = 1 + (size_t)M_TOK + (size_t)NSYM * KDIM + NSYM
                      + (size_t)NSYM * KDIM;               // 16,818,177
    size_t zc_n = (size_t)out_size - REST;
    const size_t n_z = (size_t)M_TOK * LAT;
    int interleaved = (zc_n >= 2 * n_z) ? 1 : 0;

    float* out_zc   = out;
    float* out_loss = out + zc_n;
    float* out_idx  = out + zc_n + 1;
    float* out_cb   = out + zc_n + 1 + M_TOK;
    float* out_cs   = out_cb + (size_t)NSYM * KDIM;
    float* out_ea   = out_cs + NSYM;

    // scratch, phase 1 (screen inputs), carved from output regions:
    u16*   A_hi  = (u16*)out_zc;                       // 67.1 MB (zc region)
    u16*   B_hi  = (u16*)out_cb;                       // 16.8 MB (cb region)
    float* cnorm = out_cb + 4194304;                   // 32 KB after B_hi
    float* candV = out_ea;                             // 25.2 MB [192][M]
    u16*   candI = (u16*)(out_cb + 4202496);           // 8.4 MB  [128][M] (cb free area)

    // scratch, phase 2 (EMA sort), in zc region (A_hi dead after screen; k_zq runs last):
    u32*   counts  = (u32*)out_zc;                     // 32 KB
    u32*   cursors = counts + NSYM;                    // 32 KB
    u32*   offsets = cursors + NSYM;                   // 32 KB
    u32*   list    = offsets + NSYM;                   // 128 KB
    float* scal    = (float*)(list + M_TOK);           // 8 B

    k_convA<<<16384, 256, 0, stream>>>(z_real, z_imag, A_hi);
    k_convB<<<4096, 256, 0, stream>>>(codebook, B_hi, cnorm);
    k_screen<<<1024, 256, 0, stream>>>(A_hi, B_hi, cnorm, candV, candI);
    k_zero<<<32, 256, 0, stream>>>(counts, cursors, out_loss);
    k_select<<<M_TOK / SEL_TOK, 256, 0, stream>>>(z_real, z_imag, prev_idx,
                                                  codebook, adjacency,
                                                  candV, candI, out_idx, counts);
    k_scan<<<1, 1024, 0, stream>>>(counts, cluster_sz, out_cs, offsets, scal);
    k_place<<<M_TOK / 256, 256, 0, stream>>>(out_idx, offsets, cursors, list);
    k_emit<<<NSYM, 256, 0, stream>>>(z_real, z_imag, embed_avg, counts, offsets,
                                     list, out_cs, scal, out_ea, out_cb);
    k_zq<<<M_TOK / 4, 256, 0, stream>>>(z_real, z_imag, codebook, out_idx,
                                        out_zc, out_loss, interleaved);
    k_fin<<<1, 1, 0, stream>>>(out_loss);
}